// Round 21
// baseline (142.024 us; speedup 1.0000x reference)
//
#include <hip/hip_runtime.h>
#include <hip/hip_bf16.h>

typedef __attribute__((ext_vector_type(8))) short short8;
typedef __attribute__((ext_vector_type(4))) float f32x4;

#define NTOK   100000
#define H      150
#define NSL    40          // 2 tiles x 20 K-slabs on one continuous pipeline
#define LBUF   18432       // per-slab LDS: 8KB X (64x32 fp32 swz) + 10KB B
#define OUTOFF (NTOK * H)
#define AS1 __attribute__((address_space(1)))
#define AS3 __attribute__((address_space(3)))
#define VWAIT(n) asm volatile("s_waitcnt vmcnt(" #n ")" ::: "memory")

__device__ __forceinline__ unsigned short f2bf(float f) {
    unsigned int u = __builtin_bit_cast(unsigned int, f);
    u = (u + 0x7FFFu + ((u >> 16) & 1u)) >> 16;   // RNE
    return (unsigned short)u;
}

// ---------------------------------------------------------------------------
// Prepass (r19-identical): pack weights K-SLAB-major:
// wb[((ks*10 + n)*64 + lane)*8 + j]. Window: s5<4 -> k2 = s5*32 + p;
// s5==4 -> k2 = 118 + p (in-row), p<10 zeroed (overlap). col>=150 zeroed.
// ---------------------------------------------------------------------------
__global__ void prep_w(const float* __restrict__ w_in, const float* __restrict__ w_out,
                       const float* __restrict__ u_in, const float* __restrict__ u_out,
                       unsigned short* __restrict__ wb) {
    int idx = blockIdx.x * 256 + threadIdx.x;
    if (idx >= 20 * 10 * 512) return;            // 102400 elems
    int j    = idx & 7;
    int lane = (idx >> 3) & 63;
    int n    = (idx >> 9) % 10;
    int ks   = idx / 5120;
    int seg  = ks / 5, s5 = ks % 5;
    int col  = n * 16 + (lane & 15);
    int p    = (lane >> 4) * 8 + j;
    int k2   = (s5 < 4) ? (s5 * 32 + p) : (118 + p);
    float v = 0.0f;
    if (col < H && !(s5 == 4 && p < 10)) {
        const float* W = (seg == 0) ? w_in : (seg == 1) ? w_out : (seg == 2) ? u_in : u_out;
        v = W[k2 * H + col];
    }
    wb[idx] = f2bf(v);
}

// ---------------------------------------------------------------------------
// Main fused kernel: r19 K-slab ring-4 pipeline, TWO 64-row tiles per block
// on one continuous 40-slab schedule. 8 waves (4M x 2N), each 16 rows x 80
// cols per tile. Tile0 epilogue runs at slab 19 while tile1's slabs 20-22
// are already in flight (epilogue waits vmcnt(2c) only). FIFO-exact counted
// vwaits; post-store waits target slabs BEHIND the stores (robust to the
// divergent store count).
// ---------------------------------------------------------------------------
__global__ __launch_bounds__(512, 4) void lstm_fused(
        const float* __restrict__ s_in, const float* __restrict__ s_out,
        const float* __restrict__ h_in, const float* __restrict__ h_out,
        const float* __restrict__ last_c, const unsigned short* __restrict__ wb,
        float* __restrict__ out) {
    __shared__ __align__(16) char lds[4 * LBUF];   // 73728 B -> 2 blocks/CU

    const int t     = threadIdx.x;
    const int lane  = t & 63;
    const int wid   = t >> 6;       // 0..7
    const int waveM = wid >> 1;     // 0..3 -> rows waveM*16 + [0,16)
    const int waveN = wid & 1;      // cols waveN*80 + [0,80)
    const int lrow  = lane & 15;
    const int lko   = lane >> 4;
    const int r0blk = blockIdx.x * 128;   // two 64-row tiles
    const bool cw3  = (wid < 2);    // waves 0,1: 3 chunks/slab, others: 2

    const float* Xseg[4] = {s_in, s_out, h_in, h_out};

    f32x4 acc[5];
#pragma unroll
    for (int n = 0; n < 5; n++) acc[n] = (f32x4){0.f, 0.f, 0.f, 0.f};

    float lcv[4][5];   // prefetched last_c (per tile, reused)

    // ---- stage one K-slab (X 8KB as 8 chunks, B 10KB as 10 chunks) ----
    auto stage = [&](int sl) {
        char* lb = &lds[(sl & 3) * LBUF];
        const int s5 = sl % 5;
        const int sofs = (s5 < 4) ? s5 * 128 : 472;   // in-row window offset
        const int tb = (sl >= 20) ? 64 : 0;
        const char* xb = (const char*)Xseg[(sl % 20) / 5];
        int rowg = r0blk + tb + wid * 8 + (lane >> 3);
        if (rowg > NTOK - 1) rowg = NTOK - 1;         // tail clamp (in-row reads)
        const int q = (lane & 7) ^ ((lane >> 3) & 7); // XOR-swizzled source piece
        const long go = (long)rowg * 600 + sofs + q * 16;
        __builtin_amdgcn_global_load_lds(
            (const AS1 void*)(xb + go),
            (AS3 void*)(lb + wid * 1024 + lane * 16), 16, 0, 0);
        const char* bsrc = (const char*)wb + (long)(sl % 20) * 10240;
        __builtin_amdgcn_global_load_lds(
            (const AS1 void*)(bsrc + wid * 1024 + lane * 16),
            (AS3 void*)(lb + 8192 + wid * 1024 + lane * 16), 16, 0, 0);
        if (cw3)
            __builtin_amdgcn_global_load_lds(
                (const AS1 void*)(bsrc + (8 + wid) * 1024 + lane * 16),
                (AS3 void*)(lb + 8192 + (8 + wid) * 1024 + lane * 16), 16, 0, 0);
    };

    // ---- compute one K-slab: pure LDS + VALU + MFMA ----
    auto compute = [&](int sl) {
        const char* lb = &lds[(sl & 3) * LBUF];
        const int row = waveM * 16 + lrow;
        const int r7 = lrow & 7;
        const char* xr = lb + row * 128;
        f32x4 v0 = *(const f32x4*)(xr + ((((lko << 1) | 0) ^ r7) << 4));
        f32x4 v1 = *(const f32x4*)(xr + ((((lko << 1) | 1) ^ r7) << 4));
        short8 af;
        af[0] = (short)f2bf(v0[0]); af[1] = (short)f2bf(v0[1]);
        af[2] = (short)f2bf(v0[2]); af[3] = (short)f2bf(v0[3]);
        af[4] = (short)f2bf(v1[0]); af[5] = (short)f2bf(v1[1]);
        af[6] = (short)f2bf(v1[2]); af[7] = (short)f2bf(v1[3]);
        const char* br = lb + 8192 + (waveN * 5) * 1024 + lane * 16;
        __builtin_amdgcn_s_setprio(1);
#pragma unroll
        for (int n = 0; n < 5; n++) {
            short8 bf = *(const short8*)(br + n * 1024);
            acc[n] = __builtin_amdgcn_mfma_f32_16x16x32_bf16(af, bf, acc[n], 0, 0, 0);
        }
        __builtin_amdgcn_s_setprio(0);
    };

    // ---- lc prefetch: 20 unconditional clamped loads (exact FIFO count) ----
    auto lcfetch = [&](int tb) {
#pragma unroll
        for (int r = 0; r < 4; r++) {
            int row = r0blk + tb + waveM * 16 + lko * 4 + r;
            if (row > NTOK - 1) row = NTOK - 1;
#pragma unroll
            for (int n = 0; n < 5; n++) {
                int col = waveN * 80 + n * 16 + lrow;
                if (col >= H) col = 0;
                lcv[r][n] = last_c[(long)row * H + col];
            }
        }
    };

    // ---- epilogue: g=sigmoid(pre); cell=g*lc+g*g; hid=g*tanh(cell); acc reset
    auto epilog = [&](int tb) {
#pragma unroll
        for (int r = 0; r < 4; r++) {
            const int row = r0blk + tb + waveM * 16 + lko * 4 + r;
            if (row >= NTOK) continue;
            const long rb = (long)row * H;
#pragma unroll
            for (int n = 0; n < 5; n++) {
                const int col = waveN * 80 + n * 16 + lrow;
                if (col >= H) continue;
                float pre = acc[n][r];
                float e   = __expf(-pre);
                float g   = __builtin_amdgcn_rcpf(1.f + e);
                float cell = g * lcv[r][n] + g * g;
                float e2  = __expf(-2.f * cell);
                float th  = (1.f - e2) * __builtin_amdgcn_rcpf(1.f + e2);
                out[rb + col]          = g * th;
                out[OUTOFF + rb + col] = cell;
            }
        }
#pragma unroll
        for (int n = 0; n < 5; n++) acc[n] = (f32x4){0.f, 0.f, 0.f, 0.f};
    };

    // ---- prologue: fill ring to depth 3 ----
    stage(0); stage(1); stage(2);

#pragma unroll
    for (int ks = 0; ks < NSL; ks++) {
        // counted vwaits (FIFO-exact; see header comment)
        if (ks == 18 || ks == 19)      { if (cw3) VWAIT(26); else VWAIT(24); }
        else if (ks == 20)             { /* slab 20 drained before epilogue(0) */ }
        else if (ks == 38)             { if (cw3) VWAIT(23); else VWAIT(22); }
        else if (ks == 39)             { VWAIT(20); }
        else                           { if (cw3) VWAIT(6);  else VWAIT(4);  }
        __builtin_amdgcn_s_barrier();
        asm volatile("" ::: "memory");   // no LDS-read hoisting above the barrier

        if (ks < NSL - 3) stage(ks + 3);

        if (ks == 17 || ks == 37) {
            __builtin_amdgcn_sched_barrier(0);   // pin: stage before lc loads
            lcfetch(ks == 17 ? 0 : 64);
            __builtin_amdgcn_sched_barrier(0);   // pin: lc loads before compute
        }

        compute(ks);

        if (ks == 19) {
            // drain slab20 + lc (FIFO front); tile1 slabs 21,22 stay in flight
            if (cw3) VWAIT(6); else VWAIT(4);
            __builtin_amdgcn_sched_barrier(0);
            epilog(0);
            __builtin_amdgcn_sched_barrier(0);
        }
    }

    VWAIT(0);     // tile1 lc loads landed
    epilog(64);
}

extern "C" void kernel_launch(void* const* d_in, const int* in_sizes, int n_in,
                              void* d_out, int out_size, void* d_ws, size_t ws_size,
                              hipStream_t stream) {
    const float* s_in   = (const float*)d_in[0];
    const float* s_out  = (const float*)d_in[1];
    const float* h_in   = (const float*)d_in[2];
    const float* h_out  = (const float*)d_in[3];
    const float* last_c = (const float*)d_in[4];
    const float* w_in   = (const float*)d_in[5];
    const float* w_out  = (const float*)d_in[6];
    const float* u_in   = (const float*)d_in[7];
    const float* u_out  = (const float*)d_in[8];

    unsigned short* wb = (unsigned short*)d_ws;   // 204800 B
    float* out = (float*)d_out;

    prep_w<<<(20 * 10 * 512 + 255) / 256, 256, 0, stream>>>(w_in, w_out, u_in, u_out, wb);

    const int nblocks = (NTOK + 127) / 128;  // 782 blocks, 2 tiles each
    lstm_fused<<<nblocks, 512, 0, stream>>>(s_in, s_out, h_in, h_out, last_c, wb, out);
}

// Round 22
// 117.299 us; speedup vs baseline: 1.2108x; 1.2108x over previous
//
#include <hip/hip_runtime.h>
#include <hip/hip_bf16.h>

typedef __attribute__((ext_vector_type(8))) short short8;
typedef __attribute__((ext_vector_type(4))) float f32x4;

#define NTOK   100000
#define H      150
#define NKS    20          // K-slabs; float windows start {0,32,64,96,118} (all in-row)
#define BM     64
#define LBUF   18432       // per-slab LDS: 8KB X (64x32 fp32 swz) + 10KB B
#define OUTOFF (NTOK * H)
#define AS1 __attribute__((address_space(1)))
#define AS3 __attribute__((address_space(3)))

__device__ __forceinline__ unsigned short f2bf(float f) {
    unsigned int u = __builtin_bit_cast(unsigned int, f);
    u = (u + 0x7FFFu + ((u >> 16) & 1u)) >> 16;   // RNE
    return (unsigned short)u;
}

template<int N> __device__ __forceinline__ void vwait() {
    if constexpr (N == 21)      asm volatile("s_waitcnt vmcnt(21)" ::: "memory");
    else if constexpr (N == 14) asm volatile("s_waitcnt vmcnt(14)" ::: "memory");
    else if constexpr (N == 18) asm volatile("s_waitcnt vmcnt(18)" ::: "memory");
    else if constexpr (N == 15) asm volatile("s_waitcnt vmcnt(15)" ::: "memory");
    else if constexpr (N == 12) asm volatile("s_waitcnt vmcnt(12)" ::: "memory");
    else if constexpr (N == 10) asm volatile("s_waitcnt vmcnt(10)" ::: "memory");
    else if constexpr (N == 9)  asm volatile("s_waitcnt vmcnt(9)"  ::: "memory");
    else if constexpr (N == 8)  asm volatile("s_waitcnt vmcnt(8)"  ::: "memory");
    else if constexpr (N == 6)  asm volatile("s_waitcnt vmcnt(6)"  ::: "memory");
    else if constexpr (N == 4)  asm volatile("s_waitcnt vmcnt(4)"  ::: "memory");
    else if constexpr (N == 23) asm volatile("s_waitcnt vmcnt(23)" ::: "memory");
    else if constexpr (N == 22) asm volatile("s_waitcnt vmcnt(22)" ::: "memory");
    else if constexpr (N == 20) asm volatile("s_waitcnt vmcnt(20)" ::: "memory");
    else                        asm volatile("s_waitcnt vmcnt(0)"  ::: "memory");
}

// ---------------------------------------------------------------------------
// Prepass (r19-identical): pack weights K-SLAB-major:
// wb[((ks*10 + n)*64 + lane)*8 + j]. Window: s5<4 -> k2 = s5*32 + p;
// s5==4 -> k2 = 118 + p (in-row), p<10 zeroed (overlap). col>=150 zeroed.
// ---------------------------------------------------------------------------
__global__ void prep_w(const float* __restrict__ w_in, const float* __restrict__ w_out,
                       const float* __restrict__ u_in, const float* __restrict__ u_out,
                       unsigned short* __restrict__ wb) {
    int idx = blockIdx.x * 256 + threadIdx.x;
    if (idx >= NKS * 10 * 512) return;           // 102400 elems
    int j    = idx & 7;
    int lane = (idx >> 3) & 63;
    int n    = (idx >> 9) % 10;
    int ks   = idx / 5120;
    int seg  = ks / 5, s5 = ks % 5;
    int col  = n * 16 + (lane & 15);
    int p    = (lane >> 4) * 8 + j;
    int k2   = (s5 < 4) ? (s5 * 32 + p) : (118 + p);
    float v = 0.0f;
    if (col < H && !(s5 == 4 && p < 10)) {
        const float* W = (seg == 0) ? w_in : (seg == 1) ? w_out : (seg == 2) ? u_in : u_out;
        v = W[k2 * H + col];
    }
    wb[idx] = f2bf(v);
}

// ---------------------------------------------------------------------------
// Main fused kernel: r19 structure at RING-8 / DEPTH-7 (1 block/CU).
// Block = 64 rows x 160 cols, 8 waves (4M x 2N), each 16 rows x 80 cols.
// 8-slot LDS ring (147KB). Per iter:
//   vwait(7c counted) -> s_barrier -> stage(ks+7) -> compute(ks).
// Slab cover = 7 compute phases (~4200cy) >= worst-case HBM-under-load
// latency; vmcnt never drains mid-loop. lc prefetch at ks=17 (FIFO-exact).
// ---------------------------------------------------------------------------
__global__ __launch_bounds__(512, 2) void lstm_fused(
        const float* __restrict__ s_in, const float* __restrict__ s_out,
        const float* __restrict__ h_in, const float* __restrict__ h_out,
        const float* __restrict__ last_c, const unsigned short* __restrict__ wb,
        float* __restrict__ out) {
    __shared__ __align__(16) char lds[8 * LBUF];   // 147456 B -> 1 block/CU

    const int t     = threadIdx.x;
    const int lane  = t & 63;
    const int wid   = t >> 6;       // 0..7
    const int waveM = wid >> 1;     // 0..3 -> rows waveM*16 + [0,16)
    const int waveN = wid & 1;      // cols waveN*80 + [0,80)
    const int lrow  = lane & 15;
    const int lko   = lane >> 4;
    const int r0blk = blockIdx.x * BM;
    const bool cw3  = (wid < 2);    // waves 0,1: 3 chunks/slab, others: 2

    const float* Xseg[4] = {s_in, s_out, h_in, h_out};

    f32x4 acc[5];
#pragma unroll
    for (int n = 0; n < 5; n++) acc[n] = (f32x4){0.f, 0.f, 0.f, 0.f};

    float lcv[4][5];   // prefetched last_c

    // ---- stage one K-slab (X 8KB as 8 chunks, B 10KB as 10 chunks) ----
    auto stage = [&](int sl) {
        char* lb = &lds[(sl & 7) * LBUF];
        const int s5 = sl % 5;
        const int sofs = (s5 < 4) ? s5 * 128 : 472;   // in-row window offset
        const char* xb = (const char*)Xseg[sl / 5];
        int rowg = r0blk + wid * 8 + (lane >> 3);
        if (rowg > NTOK - 1) rowg = NTOK - 1;         // tail clamp (in-row reads)
        const int q = (lane & 7) ^ ((lane >> 3) & 7); // XOR-swizzled source piece
        const long go = (long)rowg * 600 + sofs + q * 16;
        __builtin_amdgcn_global_load_lds(
            (const AS1 void*)(xb + go),
            (AS3 void*)(lb + wid * 1024 + lane * 16), 16, 0, 0);
        const char* bsrc = (const char*)wb + (long)sl * 10240;
        __builtin_amdgcn_global_load_lds(
            (const AS1 void*)(bsrc + wid * 1024 + lane * 16),
            (AS3 void*)(lb + 8192 + wid * 1024 + lane * 16), 16, 0, 0);
        if (cw3)
            __builtin_amdgcn_global_load_lds(
                (const AS1 void*)(bsrc + (8 + wid) * 1024 + lane * 16),
                (AS3 void*)(lb + 8192 + (8 + wid) * 1024 + lane * 16), 16, 0, 0);
    };

    // ---- compute one K-slab: pure LDS + VALU + MFMA ----
    auto compute = [&](int sl) {
        const char* lb = &lds[(sl & 7) * LBUF];
        const int row = waveM * 16 + lrow;
        const int r7 = lrow & 7;
        const char* xr = lb + row * 128;
        f32x4 v0 = *(const f32x4*)(xr + ((((lko << 1) | 0) ^ r7) << 4));
        f32x4 v1 = *(const f32x4*)(xr + ((((lko << 1) | 1) ^ r7) << 4));
        short8 af;
        af[0] = (short)f2bf(v0[0]); af[1] = (short)f2bf(v0[1]);
        af[2] = (short)f2bf(v0[2]); af[3] = (short)f2bf(v0[3]);
        af[4] = (short)f2bf(v1[0]); af[5] = (short)f2bf(v1[1]);
        af[6] = (short)f2bf(v1[2]); af[7] = (short)f2bf(v1[3]);
        const char* br = lb + 8192 + (waveN * 5) * 1024 + lane * 16;
        __builtin_amdgcn_s_setprio(1);
#pragma unroll
        for (int n = 0; n < 5; n++) {
            short8 bf = *(const short8*)(br + n * 1024);
            acc[n] = __builtin_amdgcn_mfma_f32_16x16x32_bf16(af, bf, acc[n], 0, 0, 0);
        }
        __builtin_amdgcn_s_setprio(0);
    };

    // ---- prologue: fill ring to depth 7 ----
    stage(0); stage(1); stage(2); stage(3); stage(4); stage(5); stage(6);

#pragma unroll
    for (int ks = 0; ks < NKS; ks++) {
        // FIFO-exact counted waits: steady 7 slabs in flight; drain tail exact.
        if (ks <= 12)      { if (cw3) vwait<21>(); else vwait<14>(); }
        else if (ks == 13) { if (cw3) vwait<18>(); else vwait<12>(); }
        else if (ks == 14) { if (cw3) vwait<15>(); else vwait<10>(); }
        else if (ks == 15) { if (cw3) vwait<12>(); else vwait<8>();  }
        else if (ks == 16) { if (cw3) vwait<9>();  else vwait<6>();  }
        else if (ks == 17) { if (cw3) vwait<6>();  else vwait<4>();  }
        else if (ks == 18) { if (cw3) vwait<23>(); else vwait<22>(); }
        else               { vwait<20>(); }
        __builtin_amdgcn_s_barrier();
        asm volatile("" ::: "memory");   // no LDS-read hoisting above the barrier

        if (ks <= 12) stage(ks + 7);

        if (ks == 17) {
            __builtin_amdgcn_sched_barrier(0);   // pin: after vwait/barrier
            // prefetch last_c: 20 unconditional clamped loads (exact FIFO count)
#pragma unroll
            for (int r = 0; r < 4; r++) {
                int row = r0blk + waveM * 16 + lko * 4 + r;
                if (row > NTOK - 1) row = NTOK - 1;
#pragma unroll
                for (int n = 0; n < 5; n++) {
                    int col = waveN * 80 + n * 16 + lrow;
                    if (col >= H) col = 0;
                    lcv[r][n] = last_c[(long)row * H + col];
                }
            }
            __builtin_amdgcn_sched_barrier(0);   // pin: lc loads before compute
        }

        compute(ks);
    }

    vwait<0>();   // lc loads landed

    // ---- fused epilogue: g=sigmoid(pre); cell=g*lc+g*g; hid=g*tanh(cell)
#pragma unroll
    for (int r = 0; r < 4; r++) {
        const int row = r0blk + waveM * 16 + lko * 4 + r;
        if (row >= NTOK) continue;
        const long rb = (long)row * H;
#pragma unroll
        for (int n = 0; n < 5; n++) {
            const int col = waveN * 80 + n * 16 + lrow;
            if (col >= H) continue;
            float pre = acc[n][r];
            float e   = __expf(-pre);
            float g   = __builtin_amdgcn_rcpf(1.f + e);
            float cell = g * lcv[r][n] + g * g;
            float e2  = __expf(-2.f * cell);
            float th  = (1.f - e2) * __builtin_amdgcn_rcpf(1.f + e2);
            out[rb + col]          = g * th;
            out[OUTOFF + rb + col] = cell;
        }
    }
}

extern "C" void kernel_launch(void* const* d_in, const int* in_sizes, int n_in,
                              void* d_out, int out_size, void* d_ws, size_t ws_size,
                              hipStream_t stream) {
    const float* s_in   = (const float*)d_in[0];
    const float* s_out  = (const float*)d_in[1];
    const float* h_in   = (const float*)d_in[2];
    const float* h_out  = (const float*)d_in[3];
    const float* last_c = (const float*)d_in[4];
    const float* w_in   = (const float*)d_in[5];
    const float* w_out  = (const float*)d_in[6];
    const float* u_in   = (const float*)d_in[7];
    const float* u_out  = (const float*)d_in[8];

    unsigned short* wb = (unsigned short*)d_ws;   // 204800 B
    float* out = (float*)d_out;

    prep_w<<<(NKS * 10 * 512 + 255) / 256, 256, 0, stream>>>(w_in, w_out, u_in, u_out, wb);

    const int nblocks = (NTOK + BM - 1) / BM;  // 1563 blocks, 8 waves (4Mx2N)
    lstm_fused<<<nblocks, 512, 0, stream>>>(s_in, s_out, h_in, h_out, last_c, wb, out);
}

// Round 23
// 113.720 us; speedup vs baseline: 1.2489x; 1.0315x over previous
//
#include <hip/hip_runtime.h>
#include <hip/hip_bf16.h>

typedef __attribute__((ext_vector_type(8))) short short8;
typedef __attribute__((ext_vector_type(4))) float f32x4;

#define NTOK   100000
#define H      150
#define NKS    20          // K-slabs; float windows start {0,32,64,96,118} (all in-row)
#define BM     64
#define LBUF   18432       // per-slab LDS: 8KB X (64x32 fp32 swz) + 10KB B
#define OUTOFF (NTOK * H)
#define AS1 __attribute__((address_space(1)))
#define AS3 __attribute__((address_space(3)))

__device__ __forceinline__ unsigned short f2bf(float f) {
    unsigned int u = __builtin_bit_cast(unsigned int, f);
    u = (u + 0x7FFFu + ((u >> 16) & 1u)) >> 16;   // RNE
    return (unsigned short)u;
}

template<int N> __device__ __forceinline__ void vwait() {
    if constexpr (N == 6)       asm volatile("s_waitcnt vmcnt(6)" ::: "memory");
    else if constexpr (N == 4)  asm volatile("s_waitcnt vmcnt(4)" ::: "memory");
    else if constexpr (N == 23) asm volatile("s_waitcnt vmcnt(23)" ::: "memory");
    else if constexpr (N == 22) asm volatile("s_waitcnt vmcnt(22)" ::: "memory");
    else if constexpr (N == 20) asm volatile("s_waitcnt vmcnt(20)" ::: "memory");
    else                        asm volatile("s_waitcnt vmcnt(0)" ::: "memory");
}

// ---------------------------------------------------------------------------
// Prepass: pack weights K-SLAB-major: wb[((ks*10 + n)*64 + lane)*8 + j].
// Window: s5<4 -> k2 = s5*32 + p; s5==4 -> k2 = 118 + p (IN-ROW, bytes
// 472..599), with p<10 ZEROED (overlap with window 3). col>=150 zeroed.
// p = (lane>>4)*8 + j;  k2 <= 149 always -> no OOB anywhere on the X side.
// ---------------------------------------------------------------------------
__global__ void prep_w(const float* __restrict__ w_in, const float* __restrict__ w_out,
                       const float* __restrict__ u_in, const float* __restrict__ u_out,
                       unsigned short* __restrict__ wb) {
    int idx = blockIdx.x * 256 + threadIdx.x;
    if (idx >= NKS * 10 * 512) return;           // 102400 elems
    int j    = idx & 7;
    int lane = (idx >> 3) & 63;
    int n    = (idx >> 9) % 10;
    int ks   = idx / 5120;
    int seg  = ks / 5, s5 = ks % 5;
    int col  = n * 16 + (lane & 15);
    int p    = (lane >> 4) * 8 + j;
    int k2   = (s5 < 4) ? (s5 * 32 + p) : (118 + p);
    float v = 0.0f;
    if (col < H && !(s5 == 4 && p < 10)) {
        const float* W = (seg == 0) ? w_in : (seg == 1) ? w_out : (seg == 2) ? u_in : u_out;
        v = W[k2 * H + col];
    }
    wb[idx] = f2bf(v);
}

// ---------------------------------------------------------------------------
// Main fused kernel (best-known, r19): K-slab ring-4 LDS pipeline, zero VMEM
// in the compute phase. Block = 64 rows x 160 cols, 8 waves (4M x 2N), each
// 16 rows x 80 cols. Per iter:
//   vwait(2*c_w) -> s_barrier -> stage(ks+3) -> compute(ks).
// ks==17: issue the 20 per-thread last_c loads (latency hides under the
// last 3 compute phases; FIFO-counted in the remaining vwaits).
// ---------------------------------------------------------------------------
__global__ __launch_bounds__(512, 4) void lstm_fused(
        const float* __restrict__ s_in, const float* __restrict__ s_out,
        const float* __restrict__ h_in, const float* __restrict__ h_out,
        const float* __restrict__ last_c, const unsigned short* __restrict__ wb,
        float* __restrict__ out) {
    __shared__ __align__(16) char lds[4 * LBUF];   // 73728 B

    const int t     = threadIdx.x;
    const int lane  = t & 63;
    const int wid   = t >> 6;       // 0..7
    const int waveM = wid >> 1;     // 0..3 -> rows waveM*16 + [0,16)
    const int waveN = wid & 1;      // cols waveN*80 + [0,80)
    const int lrow  = lane & 15;
    const int lko   = lane >> 4;
    const int r0blk = blockIdx.x * BM;
    const bool cw3  = (wid < 2);    // waves 0,1 stage 3 chunks/slab, others 2

    const float* Xseg[4] = {s_in, s_out, h_in, h_out};

    f32x4 acc[5];
#pragma unroll
    for (int n = 0; n < 5; n++) acc[n] = (f32x4){0.f, 0.f, 0.f, 0.f};

    float lcv[4][5];   // prefetched last_c values

    // ---- stage one K-slab (X 8KB as 8 chunks, B 10KB as 10 chunks) ----
    auto stage = [&](int ks2) {
        char* lb = &lds[(ks2 & 3) * LBUF];
        const int s5 = ks2 % 5;
        const int sofs = (s5 < 4) ? s5 * 128 : 472;   // window byte offset (in-row)
        // X chunk 'wid': tile rows wid*8 + (lane>>3), source piece XOR-swizzled
        {
            const char* xb = (const char*)Xseg[ks2 / 5];
            int rowg = r0blk + wid * 8 + (lane >> 3);
            if (rowg > NTOK - 1) rowg = NTOK - 1;     // tail block only; in-row reads
            const int q = (lane & 7) ^ ((lane >> 3) & 7);
            const long go = (long)rowg * 600 + sofs + q * 16;
            __builtin_amdgcn_global_load_lds(
                (const AS1 void*)(xb + go),
                (AS3 void*)(lb + wid * 1024 + lane * 16), 16, 0, 0);
        }
        // B chunks (contiguous 10KB slab in wb)
        {
            const char* bsrc = (const char*)wb + (long)ks2 * 10240;
            __builtin_amdgcn_global_load_lds(
                (const AS1 void*)(bsrc + wid * 1024 + lane * 16),
                (AS3 void*)(lb + 8192 + wid * 1024 + lane * 16), 16, 0, 0);
            if (cw3)
                __builtin_amdgcn_global_load_lds(
                    (const AS1 void*)(bsrc + (8 + wid) * 1024 + lane * 16),
                    (AS3 void*)(lb + 8192 + (8 + wid) * 1024 + lane * 16), 16, 0, 0);
        }
    };

    // ---- compute one K-slab: pure LDS + VALU + MFMA ----
    auto compute = [&](int ks2) {
        const char* lb = &lds[(ks2 & 3) * LBUF];
        const int row = waveM * 16 + lrow;
        const int r7 = lrow & 7;
        const char* xr = lb + row * 128;
        f32x4 v0 = *(const f32x4*)(xr + ((((lko << 1) | 0) ^ r7) << 4));
        f32x4 v1 = *(const f32x4*)(xr + ((((lko << 1) | 1) ^ r7) << 4));
        short8 af;
        af[0] = (short)f2bf(v0[0]); af[1] = (short)f2bf(v0[1]);
        af[2] = (short)f2bf(v0[2]); af[3] = (short)f2bf(v0[3]);
        af[4] = (short)f2bf(v1[0]); af[5] = (short)f2bf(v1[1]);
        af[6] = (short)f2bf(v1[2]); af[7] = (short)f2bf(v1[3]);
        const char* br = lb + 8192 + (waveN * 5) * 1024 + lane * 16;
        __builtin_amdgcn_s_setprio(1);
#pragma unroll
        for (int n = 0; n < 5; n++) {
            short8 bf = *(const short8*)(br + n * 1024);
            acc[n] = __builtin_amdgcn_mfma_f32_16x16x32_bf16(af, bf, acc[n], 0, 0, 0);
        }
        __builtin_amdgcn_s_setprio(0);
    };

    // ---- prologue: fill ring to depth 3 ----
    stage(0); stage(1); stage(2);

#pragma unroll
    for (int ks = 0; ks < NKS; ks++) {
        if (ks < NKS - 2)       { if (cw3) vwait<6>();  else vwait<4>();  }
        else if (ks == NKS - 2) { if (cw3) vwait<23>(); else vwait<22>(); }
        else                    vwait<20>();
        __builtin_amdgcn_s_barrier();
        asm volatile("" ::: "memory");   // no LDS-read hoisting above the barrier

        if (ks < NKS - 3) stage(ks + 3);

        if (ks == NKS - 3) {
            // prefetch last_c: 20 unconditional loads (clamped addrs -> exact
            // vmcnt count per wave); values for masked lanes unused.
#pragma unroll
            for (int r = 0; r < 4; r++) {
                int row = r0blk + waveM * 16 + lko * 4 + r;
                if (row > NTOK - 1) row = NTOK - 1;
#pragma unroll
                for (int n = 0; n < 5; n++) {
                    int col = waveN * 80 + n * 16 + lrow;
                    if (col >= H) col = 0;
                    lcv[r][n] = last_c[(long)row * H + col];
                }
            }
        }

        compute(ks);
    }

    vwait<0>();   // lc loads landed

    // ---- fused epilogue: g=sigmoid(pre); cell=g*lc+g*g; hid=g*tanh(cell)
#pragma unroll
    for (int r = 0; r < 4; r++) {
        const int row = r0blk + waveM * 16 + lko * 4 + r;
        if (row >= NTOK) continue;
        const long rb = (long)row * H;
#pragma unroll
        for (int n = 0; n < 5; n++) {
            const int col = waveN * 80 + n * 16 + lrow;
            if (col >= H) continue;
            float pre = acc[n][r];
            float e   = __expf(-pre);
            float g   = __builtin_amdgcn_rcpf(1.f + e);
            float cell = g * lcv[r][n] + g * g;
            float e2  = __expf(-2.f * cell);
            float th  = (1.f - e2) * __builtin_amdgcn_rcpf(1.f + e2);
            out[rb + col]          = g * th;
            out[OUTOFF + rb + col] = cell;
        }
    }
}

extern "C" void kernel_launch(void* const* d_in, const int* in_sizes, int n_in,
                              void* d_out, int out_size, void* d_ws, size_t ws_size,
                              hipStream_t stream) {
    const float* s_in   = (const float*)d_in[0];
    const float* s_out  = (const float*)d_in[1];
    const float* h_in   = (const float*)d_in[2];
    const float* h_out  = (const float*)d_in[3];
    const float* last_c = (const float*)d_in[4];
    const float* w_in   = (const float*)d_in[5];
    const float* w_out  = (const float*)d_in[6];
    const float* u_in   = (const float*)d_in[7];
    const float* u_out  = (const float*)d_in[8];

    unsigned short* wb = (unsigned short*)d_ws;   // 204800 B
    float* out = (float*)d_out;

    prep_w<<<(NKS * 10 * 512 + 255) / 256, 256, 0, stream>>>(w_in, w_out, u_in, u_out, wb);

    const int nblocks = (NTOK + BM - 1) / BM;  // 1563 blocks, 8 waves (4Mx2N)
    lstm_fused<<<nblocks, 512, 0, stream>>>(s_in, s_out, h_in, h_out, last_c, wb, out);
}